// Round 3
// baseline (115.520 us; speedup 1.0000x reference)
//
#include <hip/hip_runtime.h>
#include <stdint.h>

#define GN 4008      // reference GRID
#define OWS 128      // occ words per row (126 used, padded)
#define PW 128       // P16 words per row
#define CH 167       // x chunks
#define RPC 24       // rows per chunk; CH*RPC == GN
#define CPAD 4096    // padded column dim
#define YT 8         // y tiles
#define TW 512       // tile width (cols); YT*TW == CPAD
#define RPAD 544     // TW + TW/16 padded LDS row
#define LOCCAP 2048

static_assert(CH * RPC == GN, "chunking must cover grid exactly");
static_assert(YT * TW == CPAD, "tiles must cover padded grid");

// ---------------- K1: sparse corner-delta points from gt boxes -------------
// JAX scatter semantics: negative index wraps (+GN), still-OOB update dropped.
// Invalid points encoded with px=4095 (filtered by px<GN checks).
__global__ void k_points(const float* __restrict__ gt, int ngt,
                         uint32_t* __restrict__ pts, double* __restrict__ acc) {
    int i = blockIdx.x * blockDim.x + threadIdx.x;
    if (i == 0) *acc = 0.0;
    if (i >= ngt) return;
    float4 b = ((const float4*)gt)[i];
    int x1 = (int)rintf(b.x * 100.0f);
    int y1 = (int)rintf(b.y * 100.0f);
    int x2 = (int)rintf(b.z * 100.0f);
    int y2 = (int)rintf(b.w * 100.0f);
    int xs[4] = {x1, x1, x2 + 1, x2 + 1};
    int ys[4] = {y1, y2 + 1, y1, y2 + 1};
    uint32_t sg[4] = {1u, 0u, 0u, 1u};   // +1, -1, -1, +1
    #pragma unroll
    for (int c = 0; c < 4; ++c) {
        int x = xs[c], y = ys[c];
        if (x < 0) x += GN;
        if (y < 0) y += GN;
        uint32_t v;
        if (x >= 0 && x < GN && y >= 0 && y < GN)
            v = ((uint32_t)x << 20) | ((uint32_t)y << 8) | sg[c];
        else
            v = 0xFFFFFFFFu;   // px field = 4095 -> filtered everywhere
        pts[i * 4 + c] = v;
    }
}

// ---------------- K2: tiled occ build (single-wave blocks, no barriers) ----
// Block (c,t): rows [c*24,(c+1)*24) x cols [t*512,(t+1)*512).
// R[ry] = cumsum_x D over local columns; carry from cols < y0 accumulated
// during the same seed scan (cb0 + carrD). Emits bit-packed occ words and
// per-(chunk,col) bit counts (u16 pairs).
__global__ __launch_bounds__(64) void k_occ2(const uint32_t* __restrict__ pts, int npts,
                                             uint32_t* __restrict__ occw,
                                             uint32_t* __restrict__ colsum32) {
    __shared__ int R[RPAD];
    __shared__ uint16_t loc[LOCCAP];
    __shared__ int carrD[RPC];
    __shared__ int nloc;
    int c = blockIdx.x;
    int t = blockIdx.y;
    int r0 = c * RPC;
    int y0 = t * TW;
    int j = threadIdx.x;     // 0..63
    for (int i = j; i < RPAD; i += 64) R[i] = 0;
    if (j < RPC) carrD[j] = 0;
    if (j == 0) nloc = 0;
    __syncthreads();
    int cb0 = 0;
    for (int i = j; i < npts; i += 64) {
        uint32_t p = pts[i];
        int px = (int)(p >> 20);
        if (px >= GN) continue;
        int py = (int)((p >> 8) & 0xFFFu);
        int sg = (p & 1u) ? 1 : -1;
        int ry = py - y0;
        if (ry >= 0 && ry < TW) {
            if (px < r0) {
                atomicAdd(&R[ry + (ry >> 4)], sg);
            } else if (px < r0 + RPC) {
                int k = atomicAdd(&nloc, 1);
                if (k < LOCCAP)
                    loc[k] = (uint16_t)(((px - r0) << 10) | (ry << 1) | (p & 1u));
            }
        } else if (py < y0) {
            if (px < r0) cb0 += sg;
            else if (px < r0 + RPC) atomicAdd(&carrD[px - r0], sg);
        }
    }
    __syncthreads();
    // every lane gets total carry for cols < y0, rows < r0
    #pragma unroll
    for (int d = 1; d < 64; d <<= 1) cb0 += __shfl_xor(cb0, d);
    bool ovf = (nloc > LOCCAP);
    int nl = ovf ? 0 : nloc;
    uint32_t cnt[8] = {0, 0, 0, 0, 0, 0, 0, 0};
    int cbase = cb0;
    int base = j * 8;
    for (int xr = 0; xr < RPC; ++xr) {
        int x = r0 + xr;
        // apply this row's deltas
        if (!ovf) {
            for (int i = j; i < nl; i += 64) {
                uint16_t e = loc[i];
                if ((int)(e >> 10) == xr) {
                    int ry = (int)((e >> 1) & 0x1FFu);
                    atomicAdd(&R[ry + (ry >> 4)], (e & 1u) ? 1 : -1);
                }
            }
        } else {            // correctness fallback, never hit on random data
            for (int i = j; i < npts; i += 64) {
                uint32_t p = pts[i];
                if ((int)(p >> 20) != x) continue;
                int ry = (int)((p >> 8) & 0xFFFu) - y0;
                if (ry >= 0 && ry < TW) atomicAdd(&R[ry + (ry >> 4)], (p & 1u) ? 1 : -1);
            }
        }
        __syncthreads();
        cbase += carrD[xr];
        int v[8], s = 0;
        #pragma unroll
        for (int k = 0; k < 8; ++k) {
            int col = base + k;
            s += R[col + (col >> 4)];
            v[k] = s;
        }
        int ss = s;
        #pragma unroll
        for (int d = 1; d < 64; d <<= 1) {
            int tmp = __shfl_up(ss, d);
            if (j >= d) ss += tmp;
        }
        int excl = ss - s + cbase;
        uint32_t m = 0;
        #pragma unroll
        for (int k = 0; k < 8; ++k) {
            int gy = y0 + base + k;
            if (gy < GN && (excl + v[k]) > 0) m |= (1u << k);
        }
        #pragma unroll
        for (int k = 0; k < 8; ++k) cnt[k] += (m >> k) & 1u;
        // assemble 32-bit word across each quad of lanes
        uint32_t w = m << (8 * (j & 3));
        w |= __shfl_xor(w, 1);
        w |= __shfl_xor(w, 2);
        if ((j & 3) == 0)
            occw[(size_t)x * OWS + t * 16 + (j >> 2)] = w;
        __syncthreads();
    }
    uint32_t* cs = colsum32 + (((size_t)c * CPAD + y0 + base) >> 1);
    #pragma unroll
    for (int q = 0; q < 4; ++q)
        cs[q] = cnt[2 * q] | (cnt[2 * q + 1] << 16);
}

// ---------------- K3: P16 = per-row exclusive word-popcount prefix ---------
// One wave per row; lane j owns words 2j,2j+1.
__global__ __launch_bounds__(256) void k_p16(const uint32_t* __restrict__ occw,
                                             uint32_t* __restrict__ P16_32) {
    int wid = threadIdx.x >> 6, j = threadIdx.x & 63;
    int x = blockIdx.x * 4 + wid;
    if (x >= GN) return;
    uint2 w = ((const uint2*)(occw + (size_t)x * OWS))[j];
    int p0 = __popc(w.x), p1 = __popc(w.y);
    int tot = p0 + p1;
    int ss = tot;
    #pragma unroll
    for (int d = 1; d < 64; d <<= 1) {
        int tmp = __shfl_up(ss, d);
        if (j >= d) ss += tmp;
    }
    int excl = ss - tot;
    P16_32[(size_t)x * (PW / 2) + j] = (uint32_t)excl | ((uint32_t)(excl + p0) << 16);
}

// ---------------- K4: vertical exclusive scan of chunk colsums (packed) ----
// Two u16 columns per u32; halves never carry across (counts < 2^16).
__global__ __launch_bounds__(256) void k_vscanc(const uint32_t* __restrict__ colsum32,
                                                uint32_t* __restrict__ Vc32) {
    int yw = blockIdx.x * 256 + threadIdx.x;    // 2048 words
    uint32_t run = 0;
    Vc32[yw] = 0;
    #pragma unroll 8
    for (int c = 0; c < CH; ++c) {
        run += colsum32[(size_t)c * (CPAD / 2) + yw];
        Vc32[(size_t)(c + 1) * (CPAD / 2) + yw] = run;
    }
}

// ---------------- K5: horizontal inclusive scan of Vc rows -> Ic -----------
__global__ __launch_bounds__(256) void k_hscanc(const uint16_t* __restrict__ Vc,
                                                int* __restrict__ Ic) {
    __shared__ int wsum[4];
    int c = blockIdx.x, t = threadIdx.x;
    const uint32_t* row = (const uint32_t*)(Vc + (size_t)c * CPAD);
    const int4* p = (const int4*)(row + (size_t)t * 8);
    int4 A = p[0];
    int4 B = p[1];
    uint32_t w[8] = {(uint32_t)A.x, (uint32_t)A.y, (uint32_t)A.z, (uint32_t)A.w,
                     (uint32_t)B.x, (uint32_t)B.y, (uint32_t)B.z, (uint32_t)B.w};
    int v[16], s = 0;
    #pragma unroll
    for (int q = 0; q < 8; ++q) {
        s += (int)(w[q] & 0xFFFFu); v[2 * q] = s;
        s += (int)(w[q] >> 16);     v[2 * q + 1] = s;
    }
    int lane = t & 63, wid = t >> 6;
    int ss = s;
    #pragma unroll
    for (int d = 1; d < 64; d <<= 1) {
        int tmp = __shfl_up(ss, d);
        if (lane >= d) ss += tmp;
    }
    if (lane == 63) wsum[wid] = ss;
    __syncthreads();
    int carry = ss - s;
    #pragma unroll
    for (int w2 = 0; w2 < 4; ++w2) if (w2 < wid) carry += wsum[w2];
    int4* o = (int4*)(Ic + (size_t)c * CPAD + (size_t)t * 16);
    #pragma unroll
    for (int q = 0; q < 4; ++q)
        o[q] = make_int4(v[4 * q + 0] + carry, v[4 * q + 1] + carry,
                         v[4 * q + 2] + carry, v[4 * q + 3] + carry);
}

// ---------------- K6: gather (one thread per box-corner) + reduce ----------
__device__ __forceinline__ int clampI(int a) {
    return a < 0 ? 0 : (a > GN ? GN : a);
}

__global__ __launch_bounds__(256) void k_gather(const float* __restrict__ pred, int npred,
                                                const int* __restrict__ Ic,
                                                const uint16_t* __restrict__ P16,
                                                const uint32_t* __restrict__ occw,
                                                double* __restrict__ acc) {
    __shared__ double red[4];
    int g = blockIdx.x * 256 + threadIdx.x;
    int i = g >> 2, k = g & 3;
    double l = 0.0;
    int x1 = 0, y1 = 0, x2 = 0, y2 = 0;
    int cov = 0;
    if (i < npred) {
        float4 bx = ((const float4*)pred)[i];
        x1 = (int)rintf(bx.x * 100.0f);
        y1 = (int)rintf(bx.y * 100.0f);
        x2 = (int)rintf(bx.z * 100.0f);
        y2 = (int)rintf(bx.w * 100.0f);
        int a1 = clampI(x1), b1 = clampI(y1), a2 = clampI(x2), b2 = clampI(y2);
        int a = (k & 1) ? a1 : a2;
        int b = (k & 2) ? b1 : b2;
        int sgn = ((k ^ (k >> 1)) & 1) ? -1 : 1;
        int Iv = 0;
        if (a > 0 && b > 0) {
            int c = a / RPC;
            Iv = Ic[(size_t)c * CPAD + (b - 1)];
            int bw = b >> 5;
            uint32_t mask = (1u << (b & 31)) - 1u;   // b&31==0 -> 0
            #pragma unroll 4
            for (int x = c * RPC; x < a; ++x)
                Iv += (int)P16[(size_t)x * PW + bw] + __popc(occw[(size_t)x * OWS + bw] & mask);
        }
        cov = sgn * Iv;
    }
    cov += __shfl_xor(cov, 1);
    cov += __shfl_xor(cov, 2);
    if (i < npred && k == 0) {
        int area = (x2 - x1) * (y2 - y1);
        bool valid = (x2 > x1) && (y2 > y1);
        float iou = valid ? ((float)cov / fmaxf((float)area, 1.0f)) : 0.0f;
        l = (double)(1.0f - iou);
    }
    #pragma unroll
    for (int d = 32; d > 0; d >>= 1) l += __shfl_down(l, d);
    int lane = threadIdx.x & 63, wid = threadIdx.x >> 6;
    if (lane == 0) red[wid] = l;
    __syncthreads();
    if (threadIdx.x == 0)
        atomicAdd(acc, red[0] + red[1] + red[2] + red[3]);
}

// ---------------- K7: finalize ---------------------------------------------
__global__ void k_final(const double* __restrict__ acc, float* __restrict__ out, int npred) {
    out[0] = (float)(*acc / (double)npred);
}

extern "C" void kernel_launch(void* const* d_in, const int* in_sizes, int n_in,
                              void* d_out, int out_size, void* d_ws, size_t ws_size,
                              hipStream_t stream) {
    const float* pred = (const float*)d_in[0];
    // d_in[1] = target, unused by the reference loss
    const float* gt = (const float*)d_in[2];
    int npred = in_sizes[0] / 4;
    int ngt = in_sizes[2] / 4;
    int npts = ngt * 4;

    char* ws = (char*)d_ws;
    size_t off = 0;
    auto alloc = [&](size_t bytes) {
        void* p = ws + off;
        off = (off + bytes + 255) & ~(size_t)255;
        return p;
    };
    uint32_t* occw = (uint32_t*)alloc((size_t)GN * OWS * sizeof(uint32_t));      // 2.05 MB
    int* Ic = (int*)alloc((size_t)(CH + 1) * CPAD * sizeof(int));                // 2.75 MB
    uint16_t* P16 = (uint16_t*)alloc((size_t)GN * PW * sizeof(uint16_t));        // 1.03 MB
    uint16_t* colsum = (uint16_t*)alloc((size_t)CH * CPAD * sizeof(uint16_t));   // 1.37 MB
    uint16_t* Vc = (uint16_t*)alloc((size_t)(CH + 1) * CPAD * sizeof(uint16_t)); // 1.38 MB
    uint32_t* pts = (uint32_t*)alloc((size_t)npts * sizeof(uint32_t));
    double* acc = (double*)alloc(sizeof(double));

    k_points<<<dim3((ngt + 255) / 256), dim3(256), 0, stream>>>(gt, ngt, pts, acc);
    k_occ2<<<dim3(CH, YT), dim3(64), 0, stream>>>(pts, npts, occw, (uint32_t*)colsum);
    k_p16<<<dim3((GN + 3) / 4), dim3(256), 0, stream>>>(occw, (uint32_t*)P16);
    k_vscanc<<<dim3(CPAD / 2 / 256), dim3(256), 0, stream>>>((const uint32_t*)colsum, (uint32_t*)Vc);
    k_hscanc<<<dim3(CH + 1), dim3(256), 0, stream>>>(Vc, Ic);
    k_gather<<<dim3((4 * npred + 255) / 256), dim3(256), 0, stream>>>(pred, npred, Ic, P16, occw, acc);
    k_final<<<1, 1, 0, stream>>>(acc, (float*)d_out, npred);
}